// Round 1
// 1409.312 us; speedup vs baseline: 1.3045x; 1.3045x over previous
//
#include <hip/hip_runtime.h>
#include <math.h>

#define BDIM 2
#define SEQ 2048
#define DIM 1024
#define NHEAD 8
#define DHEAD 128
#define RDIM 256
#define FDIM 4096
#define MROWS 4096   // BDIM*SEQ

typedef unsigned short u16;
typedef unsigned int u32;
typedef __attribute__((ext_vector_type(8))) short s16x8;
typedef __attribute__((ext_vector_type(4))) float f32x4;

__device__ __forceinline__ float u2f(u16 v) { return __uint_as_float((u32)v << 16); }
__device__ __forceinline__ u16 f2b(float f) {
  u32 u = __float_as_uint(f);
  u32 r = (u + 0x7fffu + ((u >> 16) & 1u)) >> 16;
  return (u16)r;
}

// ---------------- RMSNorm: one block per token, bf16 out ----------------
__global__ __launch_bounds__(256) void rmsnorm_kernel(const float* __restrict__ x,
    const float* __restrict__ w, u16* __restrict__ out)
{
  const int token = blockIdx.x, tid = threadIdx.x;
  const float* xp = x + (size_t)token * DIM;
  u16* op = out + (size_t)token * DIM;
  float4 vv = *(const float4*)(xp + tid*4);
  float ss = vv.x*vv.x + vv.y*vv.y + vv.z*vv.z + vv.w*vv.w;
  #pragma unroll
  for (int o2 = 32; o2 > 0; o2 >>= 1) ss += __shfl_xor(ss, o2, 64);
  __shared__ float red[4];
  if ((tid & 63) == 0) red[tid >> 6] = ss;
  __syncthreads();
  const float tot = red[0] + red[1] + red[2] + red[3];
  const float inv = 1.0f / (sqrtf(tot * (1.0f/(float)DIM)) + 1e-6f);
  float4 wv = *(const float4*)(w + tid*4);
  uint2 pk;
  pk.x = (u32)f2b(wv.x*vv.x*inv) | ((u32)f2b(wv.y*vv.y*inv) << 16);
  pk.y = (u32)f2b(wv.z*vv.z*inv) | ((u32)f2b(wv.w*vv.w*inv) << 16);
  *(uint2*)(op + tid*4) = pk;
}

// ---------------- weight transpose-convert: W[K,N] f32 -> WT[N,K] bf16 ----------------
__global__ __launch_bounds__(256) void transw_kernel(const float* __restrict__ W,
    u16* __restrict__ WT, int K, int N)
{
  __shared__ u16 t[32][36];
  const int lx = threadIdx.x & 31, ly = threadIdx.x >> 5;
  const int n0 = blockIdx.x*32, k0 = blockIdx.y*32;
  #pragma unroll
  for (int i = 0; i < 32; i += 8)
    t[ly+i][lx] = f2b(W[(size_t)(k0+ly+i)*N + n0 + lx]);
  __syncthreads();
  #pragma unroll
  for (int i = 0; i < 32; i += 8)
    WT[(size_t)(n0+ly+i)*K + k0 + lx] = t[lx][ly+i];
}

// ---------------- MFMA GEMM: C = A(bf16) @ WT^T + bias ----------------
#define ACT_NONE 0
#define ACT_RELU 1
#define ACT_SIGCLIP 2
#define ACT_GELU 3

template<int ACT, int RES, int OM>   // OM: 0=f32 out, 1=bf16 out, 2=both
__global__ __launch_bounds__(256) void mgemm_kernel(
    const u16* __restrict__ A, const u16* __restrict__ BT,
    const float* __restrict__ bias, float* __restrict__ Cf, u16* __restrict__ Cb,
    const float* __restrict__ res, int Md, int Nd, int Kd)
{
  __shared__ u16 Al[128*72];
  __shared__ u16 Bl[128*72];
  const int tid = threadIdx.x;
  const int lane = tid & 63, wave = tid >> 6;
  const int row0 = blockIdx.y*128, col0 = blockIdx.x*128;
  const int wm = (wave >> 1)*64, wn = (wave & 1)*64;
  const int m16 = lane & 15, quad = lane >> 4;
  const f32x4 zz = {0.f, 0.f, 0.f, 0.f};
  f32x4 acc[4][4];
  #pragma unroll
  for (int i = 0; i < 4; ++i)
    #pragma unroll
    for (int j = 0; j < 4; ++j) acc[i][j] = zz;
  const int fr = tid >> 3;          // 0..31
  const int fc = (tid & 7)*8;       // 0..56
  for (int k0 = 0; k0 < Kd; k0 += 64) {
    #pragma unroll
    for (int it = 0; it < 4; ++it) {
      const int r = it*32 + fr;
      uint4 av = *(const uint4*)(A  + (size_t)(row0 + r)*Kd + k0 + fc);
      uint4 bv = *(const uint4*)(BT + (size_t)(col0 + r)*Kd + k0 + fc);
      *(uint4*)&Al[r*72 + fc] = av;
      *(uint4*)&Bl[r*72 + fc] = bv;
    }
    __syncthreads();
    #pragma unroll
    for (int kk = 0; kk < 64; kk += 32) {
      s16x8 af[4], bf[4];
      #pragma unroll
      for (int mf = 0; mf < 4; ++mf)
        af[mf] = *(const s16x8*)&Al[(wm + mf*16 + m16)*72 + kk + quad*8];
      #pragma unroll
      for (int nf = 0; nf < 4; ++nf)
        bf[nf] = *(const s16x8*)&Bl[(wn + nf*16 + m16)*72 + kk + quad*8];
      #pragma unroll
      for (int mf = 0; mf < 4; ++mf)
        #pragma unroll
        for (int nf = 0; nf < 4; ++nf)
          acc[mf][nf] = __builtin_amdgcn_mfma_f32_16x16x32_bf16(
              af[mf], bf[nf], acc[mf][nf], 0, 0, 0);
    }
    __syncthreads();
  }
  float bv4[4];
  #pragma unroll
  for (int nf = 0; nf < 4; ++nf) bv4[nf] = bias[col0 + wn + nf*16 + m16];
  #pragma unroll
  for (int mf = 0; mf < 4; ++mf) {
    #pragma unroll
    for (int rr = 0; rr < 4; ++rr) {
      const int row = row0 + wm + mf*16 + quad*4 + rr;
      #pragma unroll
      for (int nf = 0; nf < 4; ++nf) {
        const int col = col0 + wn + nf*16 + m16;
        float v = acc[mf][nf][rr] + bv4[nf];
        if (ACT == ACT_RELU) v = fmaxf(v, 0.f);
        if (ACT == ACT_SIGCLIP) {
          v = 1.f/(1.f + __expf(-v));
          v = fminf(fmaxf(v, 1e-6f), 1.f - 1e-6f);
        }
        if (ACT == ACT_GELU) {
          float t = 0.7978845608028654f*(v + 0.044715f*v*v*v);
          v = 0.5f*v*(1.f + tanhf(t));
        }
        if (RES) v += res[(size_t)row*Nd + col];
        if (OM == 0 || OM == 2) Cf[(size_t)row*Nd + col] = v;
        if (OM == 1 || OM == 2) Cb[(size_t)row*Nd + col] = f2b(v);
      }
    }
  }
}

// ---------------- parallel chunked scan ----------------
// a = exp(cumsum(log gamma)) over t, per (b,d) channel; k16 *= a in place.
// Phase A: per-(channel, t-chunk) partial sums of log gamma.
// Phase B: each block re-derives its chunk prefix (<=31 adds) then does the
//          local sequential cumsum + apply. 256 blocks -> latency fully hidden.
#define SCH 64            // t-steps per chunk
#define NCH 32            // SEQ / SCH

__global__ __launch_bounds__(256) void scan_sums_kernel(const float* __restrict__ gm,
    float* __restrict__ ssum)
{
  const int cx = blockIdx.x;                        // chunk 0..NCH-1
  const int ch = blockIdx.y*256 + threadIdx.x;      // 0..2047
  const int b = ch >> 10, d = ch & 1023;
  const float* gp = gm + (size_t)b*SEQ*DIM + (size_t)(cx*SCH)*DIM + d;
  float s = 0.f;
  #pragma unroll 8
  for (int t = 0; t < SCH; ++t) s += __logf(gp[(size_t)t*DIM]);
  ssum[cx*2048 + ch] = s;
}

__global__ __launch_bounds__(256) void scan_apply_kernel(const float* __restrict__ gm,
    const float* __restrict__ ssum, u16* __restrict__ kk)
{
  const int cx = blockIdx.x;
  const int ch = blockIdx.y*256 + threadIdx.x;
  const int b = ch >> 10, d = ch & 1023;
  float cum = 0.f;
  for (int j = 0; j < cx; ++j) cum += ssum[j*2048 + ch];
  const float* gp = gm + (size_t)b*SEQ*DIM + (size_t)(cx*SCH)*DIM + d;
  u16* kp = kk + (size_t)b*SEQ*DIM + (size_t)(cx*SCH)*DIM + d;
  #pragma unroll 8
  for (int t = 0; t < SCH; ++t) {
    cum += __logf(gp[(size_t)t*DIM]);
    kp[(size_t)t*DIM] = f2b(u2f(kp[(size_t)t*DIM]) * __expf(cum));
  }
}

// ---------------- recurrence v3 (RW 64 -> 32) ----------------
#define RG 16
#define RNG 16
#define RC 128
#define RW 32
#define RSTEPS (RC + RW)
#define REC_LDS 157184

__global__ __launch_bounds__(256, 1) void rec3_kernel(
    const float* __restrict__ z, const float* __restrict__ gm,
    const float* __restrict__ Wg, const float* __restrict__ bgp,
    float* __restrict__ hseq, float* __restrict__ hbuf, int* __restrict__ flg)
{
  extern __shared__ char smem[];
  u16*   wg_s = (u16*)smem;                    // [1024*64] bf16, swizzled
  float* h_s  = (float*)(smem + 131072);       // [2][1152] (4-pad per 32)
  float* part = (float*)(smem + 140288);       // [2][32][65]
  float* bgs  = (float*)(smem + 156928);       // [64]
  const int tid = threadIdx.x;
  const int grp = blockIdx.x >> 4;
  const int wgi = blockIdx.x & 15;
  const int col0 = wgi * 64;
  {
    const int r0 = tid >> 4;
    const int c4 = (tid & 15) * 4;
    for (int it = 0; it < 64; ++it) {
      const int r = it*16 + r0;
      float4 wv = *(const float4*)(Wg + (size_t)r*DIM + col0 + c4);
      const int jb = c4 >> 3;
      const int sw = jb ^ ((r >> 5) & 7);
      const int base = r*64 + sw*8 + (c4 & 7);
      *(u32*)&wg_s[base]   = (u32)f2b(wv.x) | ((u32)f2b(wv.y) << 16);
      *(u32*)&wg_s[base+2] = (u32)f2b(wv.z) | ((u32)f2b(wv.w) << 16);
    }
  }
  if (tid < 64) bgs[tid] = bgp[col0 + tid];
  for (int i = tid; i < 2*1152; i += 256) h_s[i] = 0.f;
  __syncthreads();

  const int tStart = (grp == 0) ? 0 : grp*RC - RW;
  const int tOut   = grp*RC;
  const int nSteps = grp*RC + RC - tStart;

  const int jg = tid & 7;
  const int p  = tid >> 3;
  const u16* wbase = &wg_s[(p*32)*64 + (jg ^ (p & 7))*8];
  const float* h0 = &h_s[p*36];
  const float* h1 = &h_s[1152 + p*36];
  float* pp0 = &part[p*65];
  float* pp1 = &part[(32 + p)*65];

  for (int s = 0; s < nSteps; ++s) {
    const int t = tStart + s;
    float zv = 0.f, gv = 0.f;
    if (tid < 128) {
      const int bb = tid >> 6, j = tid & 63;
      const size_t zi = (size_t)bb*SEQ*DIM + (size_t)t*DIM + col0 + j;
      zv = z[zi]; gv = gm[zi];
    }
    float a0[8] = {}; float a1[8] = {};
    #pragma unroll 4
    for (int ii = 0; ii < 32; ++ii) {
      uint4 wq = *(const uint4*)(wbase + ii*64);
      const float hv0 = h0[ii], hv1 = h1[ii];
      float w0 = __uint_as_float(wq.x << 16), w1 = __uint_as_float(wq.x & 0xffff0000u);
      float w2 = __uint_as_float(wq.y << 16), w3 = __uint_as_float(wq.y & 0xffff0000u);
      float w4 = __uint_as_float(wq.z << 16), w5 = __uint_as_float(wq.z & 0xffff0000u);
      float w6 = __uint_as_float(wq.w << 16), w7 = __uint_as_float(wq.w & 0xffff0000u);
      a0[0]=fmaf(hv0,w0,a0[0]); a0[1]=fmaf(hv0,w1,a0[1]); a0[2]=fmaf(hv0,w2,a0[2]); a0[3]=fmaf(hv0,w3,a0[3]);
      a0[4]=fmaf(hv0,w4,a0[4]); a0[5]=fmaf(hv0,w5,a0[5]); a0[6]=fmaf(hv0,w6,a0[6]); a0[7]=fmaf(hv0,w7,a0[7]);
      a1[0]=fmaf(hv1,w0,a1[0]); a1[1]=fmaf(hv1,w1,a1[1]); a1[2]=fmaf(hv1,w2,a1[2]); a1[3]=fmaf(hv1,w3,a1[3]);
      a1[4]=fmaf(hv1,w4,a1[4]); a1[5]=fmaf(hv1,w5,a1[5]); a1[6]=fmaf(hv1,w6,a1[6]); a1[7]=fmaf(hv1,w7,a1[7]);
    }
    #pragma unroll
    for (int jj = 0; jj < 8; ++jj) { pp0[jg*8+jj] = a0[jj]; pp1[jg*8+jj] = a1[jj]; }
    __syncthreads();

    const int slot = s & 1;
    if (tid < 128) {
      const int bb = tid >> 6, j = tid & 63;
      float dot = bgs[j];
      const float* pr = &part[bb*32*65 + j];
      #pragma unroll
      for (int q = 0; q < 32; ++q) dot += pr[q*65];
      const float sg = 1.f/(1.f + __expf(-dot));
      const int cg = col0 + j;
      const int hix = bb*1152 + cg + ((cg >> 5) << 2);
      const float hn = zv*sg + gv*h_s[hix];
      h_s[hix] = hn;
      __hip_atomic_store(&hbuf[((slot*RNG + grp)*RG + wgi)*128 + bb*64 + j], hn,
                         __ATOMIC_RELAXED, __HIP_MEMORY_SCOPE_AGENT);
      if (t >= tOut) hseq[(size_t)bb*SEQ*DIM + (size_t)t*DIM + cg] = hn;
    }
    if (s == nSteps - 1) break;
    __syncthreads();
    if (tid == 0)
      __hip_atomic_store(&flg[((grp*RSTEPS + s)*RG + wgi)*16], 1,
                         __ATOMIC_RELAXED, __HIP_MEMORY_SCOPE_AGENT);
    if (tid < RG) {
      const int* fp = &flg[((grp*RSTEPS + s)*RG + tid)*16];
      while (__hip_atomic_load(fp, __ATOMIC_RELAXED, __HIP_MEMORY_SCOPE_AGENT) == 0) {}
    }
    asm volatile("" ::: "memory");
    __syncthreads();
    {
      const float* hb = &hbuf[(slot*RNG + grp)*RG*128];
      #pragma unroll
      for (int k = 0; k < 8; ++k) {
        const int idx = tid + k*256;
        const float val = __hip_atomic_load(&hb[idx], __ATOMIC_RELAXED,
                                            __HIP_MEMORY_SCOPE_AGENT);
        const int wgo = idx >> 7, rem = idx & 127, bb = rem >> 6, j = rem & 63;
        const int cg = wgo*64 + j;
        h_s[bb*1152 + cg + ((cg >> 5) << 2)] = val;
      }
    }
    __syncthreads();
  }
}

// ---------------- MFMA flash attention ----------------
__global__ __launch_bounds__(256) void mattn_kernel(
    const u16* __restrict__ q, const u16* __restrict__ k,
    const u16* __restrict__ v, float* __restrict__ ctx)
{
  __shared__ u16 Qs[64*136];
  __shared__ u16 Ks[64*136];
  __shared__ u16 Vt[128*72];
  __shared__ u16 Ps[4*16*72];
  const int tid = threadIdx.x;
  const int wave = tid >> 6, lane = tid & 63;
  const int m16 = lane & 15, quad = lane >> 4;
  const int qt = 31 - (int)blockIdx.x;        // heavy tiles first
  const int bh = blockIdx.y;
  const int b = bh >> 3, h = bh & 7;
  const int qbase = qt * 64;
  const u16* qp = q + (size_t)b*SEQ*DIM + (size_t)h*DHEAD;
  const u16* kp = k + (size_t)b*SEQ*DIM + (size_t)h*DHEAD;
  const u16* vp = v + (size_t)b*SEQ*DIM + (size_t)h*DHEAD;
  {
    const int r = tid >> 2, c = (tid & 3)*8;
    #pragma unroll
    for (int it = 0; it < 4; ++it)
      *(uint4*)&Qs[r*136 + c + it*32] =
          *(const uint4*)(qp + (size_t)(qbase + r)*DIM + c + it*32);
  }
  f32x4 O[8];
  const f32x4 zz = {0.f,0.f,0.f,0.f};
  #pragma unroll
  for (int i = 0; i < 8; ++i) O[i] = zz;
  float m[4] = {-3e38f,-3e38f,-3e38f,-3e38f};
  float l[4] = {0.f,0.f,0.f,0.f};
  const int q0 = qbase + wave*16 + quad*4;

  for (int kt = 0; kt <= qt; ++kt) {
    const int t0 = kt*64;
    __syncthreads();
    {
      const int r = tid >> 2, c = (tid & 3)*8;
      #pragma unroll
      for (int it = 0; it < 4; ++it)
        *(uint4*)&Ks[r*136 + c + it*32] =
            *(const uint4*)(kp + (size_t)(t0 + r)*DIM + c + it*32);
    }
    {
      const int t = tid & 63, d0 = (tid >> 6)*4;
      #pragma unroll
      for (int it = 0; it < 8; ++it) {
        const int d = d0 + it*16;
        uint2 vv = *(const uint2*)(vp + (size_t)(t0 + t)*DIM + d);
        Vt[(d+0)*72 + t] = (u16)vv.x;
        Vt[(d+1)*72 + t] = (u16)(vv.x >> 16);
        Vt[(d+2)*72 + t] = (u16)vv.y;
        Vt[(d+3)*72 + t] = (u16)(vv.y >> 16);
      }
    }
    __syncthreads();
    // ---- QK^T ----
    s16x8 af[4];
    #pragma unroll
    for (int kb = 0; kb < 4; ++kb)
      af[kb] = *(const s16x8*)&Qs[(wave*16 + m16)*136 + kb*32 + quad*8];
    f32x4 sc[4];
    #pragma unroll
    for (int nb = 0; nb < 4; ++nb) {
      f32x4 a = zz;
      #pragma unroll
      for (int kb = 0; kb < 4; ++kb) {
        s16x8 bf = *(const s16x8*)&Ks[(nb*16 + m16)*136 + kb*32 + quad*8];
        a = __builtin_amdgcn_mfma_f32_16x16x32_bf16(af[kb], bf, a, 0, 0, 0);
      }
      sc[nb] = a;
    }
    // ---- scale + causal mask ----
    const float scale = 0.08838834764831845f;
    #pragma unroll
    for (int nb = 0; nb < 4; ++nb) {
      const int tcol = t0 + nb*16 + m16;
      #pragma unroll
      for (int r = 0; r < 4; ++r)
        sc[nb][r] = (tcol > q0 + r) ? -1e30f : sc[nb][r]*scale;
    }
    // ---- online softmax (register-only) ----
    float mt[4], al[4], rs[4];
    #pragma unroll
    for (int r = 0; r < 4; ++r)
      mt[r] = fmaxf(fmaxf(sc[0][r], sc[1][r]), fmaxf(sc[2][r], sc[3][r]));
    #pragma unroll
    for (int xm = 1; xm < 16; xm <<= 1)
      #pragma unroll
      for (int r = 0; r < 4; ++r) mt[r] = fmaxf(mt[r], __shfl_xor(mt[r], xm, 64));
    #pragma unroll
    for (int r = 0; r < 4; ++r) {
      const float mn = fmaxf(m[r], mt[r]);
      al[r] = __expf(m[r] - mn);
      m[r] = mn;
      rs[r] = 0.f;
    }
    #pragma unroll
    for (int nb = 0; nb < 4; ++nb)
      #pragma unroll
      for (int r = 0; r < 4; ++r) {
        const float pe = __expf(sc[nb][r] - m[r]);
        sc[nb][r] = pe;
        rs[r] += pe;
      }
    #pragma unroll
    for (int xm = 1; xm < 16; xm <<= 1)
      #pragma unroll
      for (int r = 0; r < 4; ++r) rs[r] += __shfl_xor(rs[r], xm, 64);
    #pragma unroll
    for (int r = 0; r < 4; ++r) l[r] = l[r]*al[r] + rs[r];
    #pragma unroll
    for (int nb = 0; nb < 8; ++nb)
      #pragma unroll
      for (int r = 0; r < 4; ++r) O[nb][r] *= al[r];
    // ---- P -> wave-private LDS strip (C-layout -> A-layout) ----
    u16* psw = &Ps[wave*1152];
    #pragma unroll
    for (int nb = 0; nb < 4; ++nb)
      #pragma unroll
      for (int r = 0; r < 4; ++r)
        psw[(quad*4 + r)*72 + nb*16 + m16] = f2b(sc[nb][r]);
    s16x8 pa[2];
    #pragma unroll
    for (int kb = 0; kb < 2; ++kb)
      pa[kb] = *(const s16x8*)&psw[m16*72 + kb*32 + quad*8];
    #pragma unroll
    for (int nb = 0; nb < 8; ++nb) {
      f32x4 o = O[nb];
      #pragma unroll
      for (int kb = 0; kb < 2; ++kb) {
        s16x8 vb = *(const s16x8*)&Vt[(nb*16 + m16)*72 + kb*32 + quad*8];
        o = __builtin_amdgcn_mfma_f32_16x16x32_bf16(pa[kb], vb, o, 0, 0, 0);
      }
      O[nb] = o;
    }
  }
  // ---- epilogue ----
  float invl[4];
  #pragma unroll
  for (int r = 0; r < 4; ++r) invl[r] = 1.0f / l[r];
  float* op = ctx + (size_t)b*SEQ*DIM + (size_t)h*DHEAD;
  #pragma unroll
  for (int nb = 0; nb < 8; ++nb)
    #pragma unroll
    for (int r = 0; r < 4; ++r)
      op[(size_t)(q0 + r)*DIM + nb*16 + m16] = O[nb][r]*invl[r];
}

// ---------------- elementwise add (ctx + h) -> bf16 ----------------
__global__ __launch_bounds__(256) void add_kernel(const float* __restrict__ a,
    const float* __restrict__ b, u16* __restrict__ o)
{
  const int i = (blockIdx.x*256 + threadIdx.x) * 4;
  float4 x = *(const float4*)(a + i);
  float4 y = *(const float4*)(b + i);
  uint2 pk;
  pk.x = (u32)f2b(x.x+y.x) | ((u32)f2b(x.y+y.y) << 16);
  pk.y = (u32)f2b(x.z+y.z) | ((u32)f2b(x.w+y.w) << 16);
  *(uint2*)(o + i) = pk;
}

extern "C" void kernel_launch(void* const* d_in, const int* in_sizes, int n_in,
                              void* d_out, int out_size, void* d_ws, size_t ws_size,
                              hipStream_t stream)
{
  (void)in_sizes; (void)n_in; (void)out_size; (void)ws_size;
  const float* x   = (const float*)d_in[0];
  const float* wn1 = (const float*)d_in[1];
  const float* wn2 = (const float*)d_in[2];
  const float* Wq = (const float*)d_in[3];  const float* bq = (const float*)d_in[4];
  const float* Wk = (const float*)d_in[5];  const float* bk = (const float*)d_in[6];
  const float* Wv = (const float*)d_in[7];  const float* bv = (const float*)d_in[8];
  const float* Wz = (const float*)d_in[9];  const float* bz = (const float*)d_in[10];
  const float* Wg = (const float*)d_in[11]; const float* bg = (const float*)d_in[12];
  const float* Wd = (const float*)d_in[13]; const float* bd = (const float*)d_in[14];
  const float* Wu = (const float*)d_in[15]; const float* bu = (const float*)d_in[16];
  const float* Wo = (const float*)d_in[17]; const float* bo = (const float*)d_in[18];
  const float* Wf1 = (const float*)d_in[19]; const float* bf1 = (const float*)d_in[20];
  const float* Wf2 = (const float*)d_in[21]; const float* bf2 = (const float*)d_in[22];
  float* outp = (float*)d_out;

  float* ws = (float*)d_ws;
  const size_t NT = (size_t)MROWS * DIM;   // 4,194,304 floats (16 MiB)
  float* zb   = ws;             // dead after rec3; then hosts Wf1T
  float* gmb  = ws + NT;        // dead after rec3; then hosts Wf2T
  float* hseq = ws + 2*NT;      // dead after add; then hosts mid16 (with ctxb)
  float* ctxb = ws + 3*NT;
  float* yb   = ws + 4*NT;
  u16* xn16  = (u16*)(ws + 5*NT);
  u16* yn16  = xn16 + NT;
  u16* qb16  = (u16*)(ws + 6*NT);
  u16* add16 = qb16 + NT;
  u16* kb16  = (u16*)(ws + 7*NT);
  u16* vb16  = kb16 + NT;
  u16* zb16  = (u16*)(ws + 8*NT);
  u16* dbuf16= zb16 + NT;
  int*   flg  = (int*)(ws + 8*NT + NT/2 + NT/4);
  float* hbuf = (float*)(flg + 786432);
  float* ssum = hbuf + 2*RNG*RG*128;       // 32*2048 f32 chunk sums
  u16* mid16 = (u16*)(ws + 2*NT);
  u16* WqT = (u16*)(ws + 9*NT);
  u16* WkT = WqT + 1024*1024;
  u16* WvT = WkT + 1024*1024;
  u16* WzT = WvT + 1024*1024;
  u16* WoT = WzT + 1024*1024;
  u16* WdT = WoT + 1024*1024;
  u16* WuT = WdT + 256*1024;
  u16* Wf1T = (u16*)zb;
  u16* Wf2T = (u16*)gmb;

  transw_kernel<<<dim3(32,32), 256, 0, stream>>>(Wq, WqT, 1024, 1024);
  transw_kernel<<<dim3(32,32), 256, 0, stream>>>(Wk, WkT, 1024, 1024);
  transw_kernel<<<dim3(32,32), 256, 0, stream>>>(Wv, WvT, 1024, 1024);
  transw_kernel<<<dim3(32,32), 256, 0, stream>>>(Wz, WzT, 1024, 1024);
  transw_kernel<<<dim3(32,32), 256, 0, stream>>>(Wo, WoT, 1024, 1024);
  transw_kernel<<<dim3(8,32),  256, 0, stream>>>(Wd, WdT, 1024, 256);
  transw_kernel<<<dim3(32,8),  256, 0, stream>>>(Wu, WuT, 256, 1024);

  rmsnorm_kernel<<<MROWS, 256, 0, stream>>>(x, wn1, xn16);

  dim3 gQ(8, 32);
  mgemm_kernel<ACT_NONE,0,1><<<gQ, 256, 0, stream>>>(xn16, WqT, bq, nullptr, qb16, nullptr, MROWS, DIM, DIM);
  mgemm_kernel<ACT_NONE,0,1><<<gQ, 256, 0, stream>>>(xn16, WkT, bk, nullptr, kb16, nullptr, MROWS, DIM, DIM);
  mgemm_kernel<ACT_NONE,0,1><<<gQ, 256, 0, stream>>>(xn16, WvT, bv, nullptr, vb16, nullptr, MROWS, DIM, DIM);
  mgemm_kernel<ACT_NONE,0,2><<<gQ, 256, 0, stream>>>(xn16, WzT, bz, zb, zb16, nullptr, MROWS, DIM, DIM);

  mgemm_kernel<ACT_RELU,0,1><<<dim3(2,32), 256, 0, stream>>>(zb16, WdT, bd, nullptr, dbuf16, nullptr, MROWS, RDIM, DIM);
  mgemm_kernel<ACT_SIGCLIP,0,0><<<gQ, 256, 0, stream>>>(dbuf16, WuT, bu, gmb, nullptr, nullptr, MROWS, DIM, RDIM);

  scan_sums_kernel<<<dim3(NCH, 8), 256, 0, stream>>>(gmb, ssum);
  scan_apply_kernel<<<dim3(NCH, 8), 256, 0, stream>>>(gmb, ssum, kb16);

  hipMemsetAsync(flg, 0, 786432*sizeof(int), stream);
  rec3_kernel<<<RNG*RG, 256, REC_LDS, stream>>>(zb, gmb, Wg, bg, hseq, hbuf, flg);

  transw_kernel<<<dim3(128,32), 256, 0, stream>>>(Wf1, Wf1T, 1024, 4096);
  transw_kernel<<<dim3(32,128), 256, 0, stream>>>(Wf2, Wf2T, 4096, 1024);

  mattn_kernel<<<dim3(32, BDIM*NHEAD), 256, 0, stream>>>(qb16, kb16, vb16, ctxb);

  add_kernel<<<(int)(NT/1024), 256, 0, stream>>>(ctxb, hseq, add16);
  mgemm_kernel<ACT_NONE,1,0><<<gQ, 256, 0, stream>>>(add16, WoT, bo, yb, nullptr, x, MROWS, DIM, DIM);

  rmsnorm_kernel<<<MROWS, 256, 0, stream>>>(yb, wn2, yn16);
  mgemm_kernel<ACT_GELU,0,1><<<dim3(32,32), 256, 0, stream>>>(yn16, Wf1T, bf1, nullptr, mid16, nullptr, MROWS, FDIM, DIM);
  mgemm_kernel<ACT_NONE,1,0><<<gQ, 256, 0, stream>>>(mid16, Wf2T, bf2, outp, nullptr, yb, MROWS, DIM, FDIM);
}

// Round 2
// 1397.148 us; speedup vs baseline: 1.3158x; 1.0087x over previous
//
#include <hip/hip_runtime.h>
#include <math.h>

#define BDIM 2
#define SEQ 2048
#define DIM 1024
#define NHEAD 8
#define DHEAD 128
#define RDIM 256
#define FDIM 4096
#define MROWS 4096   // BDIM*SEQ

typedef unsigned short u16;
typedef unsigned int u32;
typedef __attribute__((ext_vector_type(8))) short s16x8;
typedef __attribute__((ext_vector_type(4))) float f32x4;

__device__ __forceinline__ float u2f(u16 v) { return __uint_as_float((u32)v << 16); }
__device__ __forceinline__ u16 f2b(float f) {
  u32 u = __float_as_uint(f);
  u32 r = (u + 0x7fffu + ((u >> 16) & 1u)) >> 16;
  return (u16)r;
}

// ---------------- RMSNorm: one block per token, bf16 out ----------------
__global__ __launch_bounds__(256) void rmsnorm_kernel(const float* __restrict__ x,
    const float* __restrict__ w, u16* __restrict__ out)
{
  const int token = blockIdx.x, tid = threadIdx.x;
  const float* xp = x + (size_t)token * DIM;
  u16* op = out + (size_t)token * DIM;
  float4 vv = *(const float4*)(xp + tid*4);
  float ss = vv.x*vv.x + vv.y*vv.y + vv.z*vv.z + vv.w*vv.w;
  #pragma unroll
  for (int o2 = 32; o2 > 0; o2 >>= 1) ss += __shfl_xor(ss, o2, 64);
  __shared__ float red[4];
  if ((tid & 63) == 0) red[tid >> 6] = ss;
  __syncthreads();
  const float tot = red[0] + red[1] + red[2] + red[3];
  const float inv = 1.0f / (sqrtf(tot * (1.0f/(float)DIM)) + 1e-6f);
  float4 wv = *(const float4*)(w + tid*4);
  uint2 pk;
  pk.x = (u32)f2b(wv.x*vv.x*inv) | ((u32)f2b(wv.y*vv.y*inv) << 16);
  pk.y = (u32)f2b(wv.z*vv.z*inv) | ((u32)f2b(wv.w*vv.w*inv) << 16);
  *(uint2*)(op + tid*4) = pk;
}

// ---------------- weight transpose-convert: W[K,N] f32 -> WT[N,K] bf16 ----------------
__global__ __launch_bounds__(256) void transw_kernel(const float* __restrict__ W,
    u16* __restrict__ WT, int K, int N)
{
  __shared__ u16 t[32][36];
  const int lx = threadIdx.x & 31, ly = threadIdx.x >> 5;
  const int n0 = blockIdx.x*32, k0 = blockIdx.y*32;
  #pragma unroll
  for (int i = 0; i < 32; i += 8)
    t[ly+i][lx] = f2b(W[(size_t)(k0+ly+i)*N + n0 + lx]);
  __syncthreads();
  #pragma unroll
  for (int i = 0; i < 32; i += 8)
    WT[(size_t)(n0+ly+i)*K + k0 + lx] = t[lx][ly+i];
}

// ---------------- MFMA GEMM: C = A(bf16) @ WT^T + bias ----------------
#define ACT_NONE 0
#define ACT_RELU 1
#define ACT_SIGCLIP 2
#define ACT_GELU 3

template<int ACT, int RES, int OM>   // OM: 0=f32 out, 1=bf16 out, 2=both
__global__ __launch_bounds__(256) void mgemm_kernel(
    const u16* __restrict__ A, const u16* __restrict__ BT,
    const float* __restrict__ bias, float* __restrict__ Cf, u16* __restrict__ Cb,
    const float* __restrict__ res, int Md, int Nd, int Kd)
{
  __shared__ u16 Al[128*72];
  __shared__ u16 Bl[128*72];
  const int tid = threadIdx.x;
  const int lane = tid & 63, wave = tid >> 6;
  const int row0 = blockIdx.y*128, col0 = blockIdx.x*128;
  const int wm = (wave >> 1)*64, wn = (wave & 1)*64;
  const int m16 = lane & 15, quad = lane >> 4;
  const f32x4 zz = {0.f, 0.f, 0.f, 0.f};
  f32x4 acc[4][4];
  #pragma unroll
  for (int i = 0; i < 4; ++i)
    #pragma unroll
    for (int j = 0; j < 4; ++j) acc[i][j] = zz;
  const int fr = tid >> 3;          // 0..31
  const int fc = (tid & 7)*8;       // 0..56
  for (int k0 = 0; k0 < Kd; k0 += 64) {
    #pragma unroll
    for (int it = 0; it < 4; ++it) {
      const int r = it*32 + fr;
      uint4 av = *(const uint4*)(A  + (size_t)(row0 + r)*Kd + k0 + fc);
      uint4 bv = *(const uint4*)(BT + (size_t)(col0 + r)*Kd + k0 + fc);
      *(uint4*)&Al[r*72 + fc] = av;
      *(uint4*)&Bl[r*72 + fc] = bv;
    }
    __syncthreads();
    #pragma unroll
    for (int kk = 0; kk < 64; kk += 32) {
      s16x8 af[4], bf[4];
      #pragma unroll
      for (int mf = 0; mf < 4; ++mf)
        af[mf] = *(const s16x8*)&Al[(wm + mf*16 + m16)*72 + kk + quad*8];
      #pragma unroll
      for (int nf = 0; nf < 4; ++nf)
        bf[nf] = *(const s16x8*)&Bl[(wn + nf*16 + m16)*72 + kk + quad*8];
      #pragma unroll
      for (int mf = 0; mf < 4; ++mf)
        #pragma unroll
        for (int nf = 0; nf < 4; ++nf)
          acc[mf][nf] = __builtin_amdgcn_mfma_f32_16x16x32_bf16(
              af[mf], bf[nf], acc[mf][nf], 0, 0, 0);
    }
    __syncthreads();
  }
  float bv4[4];
  #pragma unroll
  for (int nf = 0; nf < 4; ++nf) bv4[nf] = bias[col0 + wn + nf*16 + m16];
  #pragma unroll
  for (int mf = 0; mf < 4; ++mf) {
    #pragma unroll
    for (int rr = 0; rr < 4; ++rr) {
      const int row = row0 + wm + mf*16 + quad*4 + rr;
      #pragma unroll
      for (int nf = 0; nf < 4; ++nf) {
        const int col = col0 + wn + nf*16 + m16;
        float v = acc[mf][nf][rr] + bv4[nf];
        if (ACT == ACT_RELU) v = fmaxf(v, 0.f);
        if (ACT == ACT_SIGCLIP) {
          v = 1.f/(1.f + __expf(-v));
          v = fminf(fmaxf(v, 1e-6f), 1.f - 1e-6f);
        }
        if (ACT == ACT_GELU) {
          float t = 0.7978845608028654f*(v + 0.044715f*v*v*v);
          v = 0.5f*v*(1.f + tanhf(t));
        }
        if (RES) v += res[(size_t)row*Nd + col];
        if (OM == 0 || OM == 2) Cf[(size_t)row*Nd + col] = v;
        if (OM == 1 || OM == 2) Cb[(size_t)row*Nd + col] = f2b(v);
      }
    }
  }
}

// ---------------- parallel chunked scan ----------------
#define SCH 64            // t-steps per chunk
#define NCH 32            // SEQ / SCH

__global__ __launch_bounds__(256) void scan_sums_kernel(const float* __restrict__ gm,
    float* __restrict__ ssum)
{
  const int cx = blockIdx.x;                        // chunk 0..NCH-1
  const int ch = blockIdx.y*256 + threadIdx.x;      // 0..2047
  const int b = ch >> 10, d = ch & 1023;
  const float* gp = gm + (size_t)b*SEQ*DIM + (size_t)(cx*SCH)*DIM + d;
  float s = 0.f;
  #pragma unroll 8
  for (int t = 0; t < SCH; ++t) s += __logf(gp[(size_t)t*DIM]);
  ssum[cx*2048 + ch] = s;
}

__global__ __launch_bounds__(256) void scan_apply_kernel(const float* __restrict__ gm,
    const float* __restrict__ ssum, u16* __restrict__ kk)
{
  const int cx = blockIdx.x;
  const int ch = blockIdx.y*256 + threadIdx.x;
  const int b = ch >> 10, d = ch & 1023;
  float cum = 0.f;
  for (int j = 0; j < cx; ++j) cum += ssum[j*2048 + ch];
  const float* gp = gm + (size_t)b*SEQ*DIM + (size_t)(cx*SCH)*DIM + d;
  u16* kp = kk + (size_t)b*SEQ*DIM + (size_t)(cx*SCH)*DIM + d;
  #pragma unroll 8
  for (int t = 0; t < SCH; ++t) {
    cum += __logf(gp[(size_t)t*DIM]);
    kp[(size_t)t*DIM] = f2b(u2f(kp[(size_t)t*DIM]) * __expf(cum));
  }
}

// ---------------- recurrence v4: RG=8 (128 cols/WG), RNG=32, 512 threads ----------------
// Wg slice 256KB: cols [0,64) in LDS (swizzled, 128KB), cols [64,128) in VGPRs
// (waves 4..7, 32 rows x 8 cols packed bf16 = 128 VGPRs/lane, wave-uniform branch).
// Cross-p2 partial reduce via 3x shfl_xor keeps LDS part array at 5KB.
#define RG 8
#define RNG 32
#define RC 64
#define RW 32
#define RSTEPS (RC + RW)    // 96
#define REC_LDS 145920

__global__ __launch_bounds__(512, 2) void rec3_kernel(
    const float* __restrict__ z, const float* __restrict__ gm,
    const float* __restrict__ Wg, const float* __restrict__ bgp,
    float* __restrict__ hseq, float* __restrict__ hbuf, int* __restrict__ flg)
{
  extern __shared__ char smem[];
  u16*   wg_s = (u16*)smem;                    // [1024*64] bf16, swizzled (128KB)
  float* h_s  = (float*)(smem + 131072);       // [2][1152] (4-pad per 32)
  float* part = (float*)(smem + 140288);       // [2][128][5]
  float* bgs  = (float*)(smem + 145408);       // [128]
  const int tid = threadIdx.x;
  const int wave = tid >> 6, lane = tid & 63;
  const int p2 = lane >> 3, jg = lane & 7;
  const int ch = wave >> 2, sub = wave & 3;
  const int rbase = sub*8 + p2;                // row-group 0..31 (32 rows each)
  const int grp = blockIdx.x & 31;             // group members share blockIdx%32 -> same XCD
  const int wgi = blockIdx.x >> 5;
  const int col0 = wgi * 128;

  // LDS half: cols [col0, col0+64)
  {
    const int r0 = tid >> 4;
    const int c4 = (tid & 15) * 4;
    for (int it = 0; it < 32; ++it) {
      const int r = it*32 + r0;
      float4 wv = *(const float4*)(Wg + (size_t)r*DIM + col0 + c4);
      const int jb = c4 >> 3;
      const int sw = jb ^ ((r >> 5) & 7);
      const int base = r*64 + sw*8 + (c4 & 7);
      *(u32*)&wg_s[base]   = (u32)f2b(wv.x) | ((u32)f2b(wv.y) << 16);
      *(u32*)&wg_s[base+2] = (u32)f2b(wv.z) | ((u32)f2b(wv.w) << 16);
    }
  }
  // register half: cols [col0+64, col0+128), held by waves 4..7
  uint4 wr[32];
  if (ch == 1) {
    const float* wp = Wg + (size_t)(rbase*32)*DIM + col0 + 64 + jg*8;
    #pragma unroll
    for (int ii = 0; ii < 32; ++ii) {
      float4 wa = *(const float4*)(wp + (size_t)ii*DIM);
      float4 wb = *(const float4*)(wp + (size_t)ii*DIM + 4);
      wr[ii].x = (u32)f2b(wa.x) | ((u32)f2b(wa.y) << 16);
      wr[ii].y = (u32)f2b(wa.z) | ((u32)f2b(wa.w) << 16);
      wr[ii].z = (u32)f2b(wb.x) | ((u32)f2b(wb.y) << 16);
      wr[ii].w = (u32)f2b(wb.z) | ((u32)f2b(wb.w) << 16);
    }
  }
  if (tid < 128) bgs[tid] = bgp[col0 + tid];
  for (int i = tid; i < 2*1152; i += 512) h_s[i] = 0.f;
  __syncthreads();

  const int tStart = (grp == 0) ? 0 : grp*RC - RW;
  const int tOut   = grp*RC;
  const int nSteps = grp*RC + RC - tStart;

  const u16* wbase = &wg_s[(rbase*32)*64 + (jg ^ p2)*8];
  const float* h0 = &h_s[rbase*36];
  const float* h1 = &h_s[1152 + rbase*36];

  for (int s = 0; s < nSteps; ++s) {
    const int t = tStart + s;
    float zv = 0.f, gv = 0.f;
    if (tid < 256) {
      const int bb = tid >> 7, j = tid & 127;
      const size_t zi = (size_t)bb*SEQ*DIM + (size_t)t*DIM + col0 + j;
      zv = z[zi]; gv = gm[zi];
    }
    float a0[8] = {}; float a1[8] = {};
    if (ch == 0) {
      #pragma unroll 4
      for (int ii = 0; ii < 32; ++ii) {
        uint4 wq = *(const uint4*)(wbase + ii*64);
        const float hv0 = h0[ii], hv1 = h1[ii];
        float w0 = __uint_as_float(wq.x << 16), w1 = __uint_as_float(wq.x & 0xffff0000u);
        float w2 = __uint_as_float(wq.y << 16), w3 = __uint_as_float(wq.y & 0xffff0000u);
        float w4 = __uint_as_float(wq.z << 16), w5 = __uint_as_float(wq.z & 0xffff0000u);
        float w6 = __uint_as_float(wq.w << 16), w7 = __uint_as_float(wq.w & 0xffff0000u);
        a0[0]=fmaf(hv0,w0,a0[0]); a0[1]=fmaf(hv0,w1,a0[1]); a0[2]=fmaf(hv0,w2,a0[2]); a0[3]=fmaf(hv0,w3,a0[3]);
        a0[4]=fmaf(hv0,w4,a0[4]); a0[5]=fmaf(hv0,w5,a0[5]); a0[6]=fmaf(hv0,w6,a0[6]); a0[7]=fmaf(hv0,w7,a0[7]);
        a1[0]=fmaf(hv1,w0,a1[0]); a1[1]=fmaf(hv1,w1,a1[1]); a1[2]=fmaf(hv1,w2,a1[2]); a1[3]=fmaf(hv1,w3,a1[3]);
        a1[4]=fmaf(hv1,w4,a1[4]); a1[5]=fmaf(hv1,w5,a1[5]); a1[6]=fmaf(hv1,w6,a1[6]); a1[7]=fmaf(hv1,w7,a1[7]);
      }
    } else {
      #pragma unroll
      for (int ii = 0; ii < 32; ++ii) {
        const uint4 wq = wr[ii];
        const float hv0 = h0[ii], hv1 = h1[ii];
        float w0 = __uint_as_float(wq.x << 16), w1 = __uint_as_float(wq.x & 0xffff0000u);
        float w2 = __uint_as_float(wq.y << 16), w3 = __uint_as_float(wq.y & 0xffff0000u);
        float w4 = __uint_as_float(wq.z << 16), w5 = __uint_as_float(wq.z & 0xffff0000u);
        float w6 = __uint_as_float(wq.w << 16), w7 = __uint_as_float(wq.w & 0xffff0000u);
        a0[0]=fmaf(hv0,w0,a0[0]); a0[1]=fmaf(hv0,w1,a0[1]); a0[2]=fmaf(hv0,w2,a0[2]); a0[3]=fmaf(hv0,w3,a0[3]);
        a0[4]=fmaf(hv0,w4,a0[4]); a0[5]=fmaf(hv0,w5,a0[5]); a0[6]=fmaf(hv0,w6,a0[6]); a0[7]=fmaf(hv0,w7,a0[7]);
        a1[0]=fmaf(hv1,w0,a1[0]); a1[1]=fmaf(hv1,w1,a1[1]); a1[2]=fmaf(hv1,w2,a1[2]); a1[3]=fmaf(hv1,w3,a1[3]);
        a1[4]=fmaf(hv1,w4,a1[4]); a1[5]=fmaf(hv1,w5,a1[5]); a1[6]=fmaf(hv1,w6,a1[6]); a1[7]=fmaf(hv1,w7,a1[7]);
      }
    }
    // cross-p2 in-wave reduce: 8 row-groups -> 1
    #pragma unroll
    for (int jj = 0; jj < 8; ++jj) {
      a0[jj] += __shfl_xor(a0[jj], 8, 64);
      a0[jj] += __shfl_xor(a0[jj], 16, 64);
      a0[jj] += __shfl_xor(a0[jj], 32, 64);
      a1[jj] += __shfl_xor(a1[jj], 8, 64);
      a1[jj] += __shfl_xor(a1[jj], 16, 64);
      a1[jj] += __shfl_xor(a1[jj], 32, 64);
    }
    if (p2 == 0) {
      const int colb = ch*64 + jg*8;
      #pragma unroll
      for (int jj = 0; jj < 8; ++jj) {
        part[(colb + jj)*5 + sub] = a0[jj];
        part[640 + (colb + jj)*5 + sub] = a1[jj];
      }
    }
    __syncthreads();

    const int slot = s & 1;
    if (tid < 256) {
      const int bb = tid >> 7, j = tid & 127;
      const float* pr = &part[bb*640 + j*5];
      const float dot = bgs[j] + pr[0] + pr[1] + pr[2] + pr[3];
      const float sg = 1.f/(1.f + __expf(-dot));
      const int cg = col0 + j;
      const int hix = bb*1152 + cg + ((cg >> 5) << 2);
      const float hn = zv*sg + gv*h_s[hix];
      h_s[hix] = hn;
      __hip_atomic_store(&hbuf[((slot*RNG + grp)*RG + wgi)*256 + bb*128 + j], hn,
                         __ATOMIC_RELAXED, __HIP_MEMORY_SCOPE_AGENT);
      if (t >= tOut) hseq[(size_t)bb*SEQ*DIM + (size_t)t*DIM + cg] = hn;
    }
    if (s == nSteps - 1) break;
    __syncthreads();
    if (tid == 0)
      __hip_atomic_store(&flg[((grp*RSTEPS + s)*RG + wgi)*16], 1,
                         __ATOMIC_RELAXED, __HIP_MEMORY_SCOPE_AGENT);
    if (tid < RG) {
      const int* fp = &flg[((grp*RSTEPS + s)*RG + tid)*16];
      while (__hip_atomic_load(fp, __ATOMIC_RELAXED, __HIP_MEMORY_SCOPE_AGENT) == 0) {}
    }
    asm volatile("" ::: "memory");
    __syncthreads();
    {
      const float* hb = &hbuf[(slot*RNG + grp)*RG*256];
      #pragma unroll
      for (int k = 0; k < 4; ++k) {
        const int idx = tid + k*512;
        const float val = __hip_atomic_load(&hb[idx], __ATOMIC_RELAXED,
                                            __HIP_MEMORY_SCOPE_AGENT);
        const int wgo = idx >> 8, rem = idx & 255, bb = rem >> 7, j = rem & 127;
        const int cg = wgo*128 + j;
        h_s[bb*1152 + cg + ((cg >> 5) << 2)] = val;
      }
    }
    __syncthreads();
  }
}

// ---------------- MFMA flash attention ----------------
__global__ __launch_bounds__(256) void mattn_kernel(
    const u16* __restrict__ q, const u16* __restrict__ k,
    const u16* __restrict__ v, float* __restrict__ ctx)
{
  __shared__ u16 Qs[64*136];
  __shared__ u16 Ks[64*136];
  __shared__ u16 Vt[128*72];
  __shared__ u16 Ps[4*16*72];
  const int tid = threadIdx.x;
  const int wave = tid >> 6, lane = tid & 63;
  const int m16 = lane & 15, quad = lane >> 4;
  const int qt = 31 - (int)blockIdx.x;        // heavy tiles first
  const int bh = blockIdx.y;
  const int b = bh >> 3, h = bh & 7;
  const int qbase = qt * 64;
  const u16* qp = q + (size_t)b*SEQ*DIM + (size_t)h*DHEAD;
  const u16* kp = k + (size_t)b*SEQ*DIM + (size_t)h*DHEAD;
  const u16* vp = v + (size_t)b*SEQ*DIM + (size_t)h*DHEAD;
  {
    const int r = tid >> 2, c = (tid & 3)*8;
    #pragma unroll
    for (int it = 0; it < 4; ++it)
      *(uint4*)&Qs[r*136 + c + it*32] =
          *(const uint4*)(qp + (size_t)(qbase + r)*DIM + c + it*32);
  }
  f32x4 O[8];
  const f32x4 zz = {0.f,0.f,0.f,0.f};
  #pragma unroll
  for (int i = 0; i < 8; ++i) O[i] = zz;
  float m[4] = {-3e38f,-3e38f,-3e38f,-3e38f};
  float l[4] = {0.f,0.f,0.f,0.f};
  const int q0 = qbase + wave*16 + quad*4;

  for (int kt = 0; kt <= qt; ++kt) {
    const int t0 = kt*64;
    __syncthreads();
    {
      const int r = tid >> 2, c = (tid & 3)*8;
      #pragma unroll
      for (int it = 0; it < 4; ++it)
        *(uint4*)&Ks[r*136 + c + it*32] =
            *(const uint4*)(kp + (size_t)(t0 + r)*DIM + c + it*32);
    }
    {
      const int t = tid & 63, d0 = (tid >> 6)*4;
      #pragma unroll
      for (int it = 0; it < 8; ++it) {
        const int d = d0 + it*16;
        uint2 vv = *(const uint2*)(vp + (size_t)(t0 + t)*DIM + d);
        Vt[(d+0)*72 + t] = (u16)vv.x;
        Vt[(d+1)*72 + t] = (u16)(vv.x >> 16);
        Vt[(d+2)*72 + t] = (u16)vv.y;
        Vt[(d+3)*72 + t] = (u16)(vv.y >> 16);
      }
    }
    __syncthreads();
    // ---- QK^T ----
    s16x8 af[4];
    #pragma unroll
    for (int kb = 0; kb < 4; ++kb)
      af[kb] = *(const s16x8*)&Qs[(wave*16 + m16)*136 + kb*32 + quad*8];
    f32x4 sc[4];
    #pragma unroll
    for (int nb = 0; nb < 4; ++nb) {
      f32x4 a = zz;
      #pragma unroll
      for (int kb = 0; kb < 4; ++kb) {
        s16x8 bf = *(const s16x8*)&Ks[(nb*16 + m16)*136 + kb*32 + quad*8];
        a = __builtin_amdgcn_mfma_f32_16x16x32_bf16(af[kb], bf, a, 0, 0, 0);
      }
      sc[nb] = a;
    }
    // ---- scale + causal mask ----
    const float scale = 0.08838834764831845f;
    #pragma unroll
    for (int nb = 0; nb < 4; ++nb) {
      const int tcol = t0 + nb*16 + m16;
      #pragma unroll
      for (int r = 0; r < 4; ++r)
        sc[nb][r] = (tcol > q0 + r) ? -1e30f : sc[nb][r]*scale;
    }
    // ---- online softmax (register-only) ----
    float mt[4], al[4], rs[4];
    #pragma unroll
    for (int r = 0; r < 4; ++r)
      mt[r] = fmaxf(fmaxf(sc[0][r], sc[1][r]), fmaxf(sc[2][r], sc[3][r]));
    #pragma unroll
    for (int xm = 1; xm < 16; xm <<= 1)
      #pragma unroll
      for (int r = 0; r < 4; ++r) mt[r] = fmaxf(mt[r], __shfl_xor(mt[r], xm, 64));
    #pragma unroll
    for (int r = 0; r < 4; ++r) {
      const float mn = fmaxf(m[r], mt[r]);
      al[r] = __expf(m[r] - mn);
      m[r] = mn;
      rs[r] = 0.f;
    }
    #pragma unroll
    for (int nb = 0; nb < 4; ++nb)
      #pragma unroll
      for (int r = 0; r < 4; ++r) {
        const float pe = __expf(sc[nb][r] - m[r]);
        sc[nb][r] = pe;
        rs[r] += pe;
      }
    #pragma unroll
    for (int xm = 1; xm < 16; xm <<= 1)
      #pragma unroll
      for (int r = 0; r < 4; ++r) rs[r] += __shfl_xor(rs[r], xm, 64);
    #pragma unroll
    for (int r = 0; r < 4; ++r) l[r] = l[r]*al[r] + rs[r];
    #pragma unroll
    for (int nb = 0; nb < 8; ++nb)
      #pragma unroll
      for (int r = 0; r < 4; ++r) O[nb][r] *= al[r];
    // ---- P -> wave-private LDS strip (C-layout -> A-layout) ----
    u16* psw = &Ps[wave*1152];
    #pragma unroll
    for (int nb = 0; nb < 4; ++nb)
      #pragma unroll
      for (int r = 0; r < 4; ++r)
        psw[(quad*4 + r)*72 + nb*16 + m16] = f2b(sc[nb][r]);
    s16x8 pa[2];
    #pragma unroll
    for (int kb = 0; kb < 2; ++kb)
      pa[kb] = *(const s16x8*)&psw[m16*72 + kb*32 + quad*8];
    #pragma unroll
    for (int nb = 0; nb < 8; ++nb) {
      f32x4 o = O[nb];
      #pragma unroll
      for (int kb = 0; kb < 2; ++kb) {
        s16x8 vb = *(const s16x8*)&Vt[(nb*16 + m16)*72 + kb*32 + quad*8];
        o = __builtin_amdgcn_mfma_f32_16x16x32_bf16(pa[kb], vb, o, 0, 0, 0);
      }
      O[nb] = o;
    }
  }
  // ---- epilogue ----
  float invl[4];
  #pragma unroll
  for (int r = 0; r < 4; ++r) invl[r] = 1.0f / l[r];
  float* op = ctx + (size_t)b*SEQ*DIM + (size_t)h*DHEAD;
  #pragma unroll
  for (int nb = 0; nb < 8; ++nb)
    #pragma unroll
    for (int r = 0; r < 4; ++r)
      op[(size_t)(q0 + r)*DIM + nb*16 + m16] = O[nb][r]*invl[r];
}

// ---------------- elementwise add (ctx + h) -> bf16 ----------------
__global__ __launch_bounds__(256) void add_kernel(const float* __restrict__ a,
    const float* __restrict__ b, u16* __restrict__ o)
{
  const int i = (blockIdx.x*256 + threadIdx.x) * 4;
  float4 x = *(const float4*)(a + i);
  float4 y = *(const float4*)(b + i);
  uint2 pk;
  pk.x = (u32)f2b(x.x+y.x) | ((u32)f2b(x.y+y.y) << 16);
  pk.y = (u32)f2b(x.z+y.z) | ((u32)f2b(x.w+y.w) << 16);
  *(uint2*)(o + i) = pk;
}

extern "C" void kernel_launch(void* const* d_in, const int* in_sizes, int n_in,
                              void* d_out, int out_size, void* d_ws, size_t ws_size,
                              hipStream_t stream)
{
  (void)in_sizes; (void)n_in; (void)out_size; (void)ws_size;
  const float* x   = (const float*)d_in[0];
  const float* wn1 = (const float*)d_in[1];
  const float* wn2 = (const float*)d_in[2];
  const float* Wq = (const float*)d_in[3];  const float* bq = (const float*)d_in[4];
  const float* Wk = (const float*)d_in[5];  const float* bk = (const float*)d_in[6];
  const float* Wv = (const float*)d_in[7];  const float* bv = (const float*)d_in[8];
  const float* Wz = (const float*)d_in[9];  const float* bz = (const float*)d_in[10];
  const float* Wg = (const float*)d_in[11]; const float* bg = (const float*)d_in[12];
  const float* Wd = (const float*)d_in[13]; const float* bd = (const float*)d_in[14];
  const float* Wu = (const float*)d_in[15]; const float* bu = (const float*)d_in[16];
  const float* Wo = (const float*)d_in[17]; const float* bo = (const float*)d_in[18];
  const float* Wf1 = (const float*)d_in[19]; const float* bf1 = (const float*)d_in[20];
  const float* Wf2 = (const float*)d_in[21]; const float* bf2 = (const float*)d_in[22];
  float* outp = (float*)d_out;

  float* ws = (float*)d_ws;
  const size_t NT = (size_t)MROWS * DIM;   // 4,194,304 floats (16 MiB)
  float* zb   = ws;             // dead after rec3; then hosts Wf1T
  float* gmb  = ws + NT;        // dead after rec3; then hosts Wf2T
  float* hseq = ws + 2*NT;      // dead after add; then hosts mid16 (with ctxb)
  float* ctxb = ws + 3*NT;
  float* yb   = ws + 4*NT;
  u16* xn16  = (u16*)(ws + 5*NT);
  u16* yn16  = xn16 + NT;
  u16* qb16  = (u16*)(ws + 6*NT);
  u16* add16 = qb16 + NT;
  u16* kb16  = (u16*)(ws + 7*NT);
  u16* vb16  = kb16 + NT;
  u16* zb16  = (u16*)(ws + 8*NT);
  u16* dbuf16= zb16 + NT;
  int*   flg  = (int*)(ws + 8*NT + NT/2 + NT/4);
  float* hbuf = (float*)(flg + 786432);
  float* ssum = hbuf + 2*RNG*RG*256;       // after 131072-float hbuf
  u16* mid16 = (u16*)(ws + 2*NT);
  u16* WqT = (u16*)(ws + 9*NT);
  u16* WkT = WqT + 1024*1024;
  u16* WvT = WkT + 1024*1024;
  u16* WzT = WvT + 1024*1024;
  u16* WoT = WzT + 1024*1024;
  u16* WdT = WoT + 1024*1024;
  u16* WuT = WdT + 256*1024;
  u16* Wf1T = (u16*)zb;
  u16* Wf2T = (u16*)gmb;

  transw_kernel<<<dim3(32,32), 256, 0, stream>>>(Wq, WqT, 1024, 1024);
  transw_kernel<<<dim3(32,32), 256, 0, stream>>>(Wk, WkT, 1024, 1024);
  transw_kernel<<<dim3(32,32), 256, 0, stream>>>(Wv, WvT, 1024, 1024);
  transw_kernel<<<dim3(32,32), 256, 0, stream>>>(Wz, WzT, 1024, 1024);
  transw_kernel<<<dim3(32,32), 256, 0, stream>>>(Wo, WoT, 1024, 1024);
  transw_kernel<<<dim3(8,32),  256, 0, stream>>>(Wd, WdT, 1024, 256);
  transw_kernel<<<dim3(32,8),  256, 0, stream>>>(Wu, WuT, 256, 1024);

  rmsnorm_kernel<<<MROWS, 256, 0, stream>>>(x, wn1, xn16);

  dim3 gQ(8, 32);
  mgemm_kernel<ACT_NONE,0,1><<<gQ, 256, 0, stream>>>(xn16, WqT, bq, nullptr, qb16, nullptr, MROWS, DIM, DIM);
  mgemm_kernel<ACT_NONE,0,1><<<gQ, 256, 0, stream>>>(xn16, WkT, bk, nullptr, kb16, nullptr, MROWS, DIM, DIM);
  mgemm_kernel<ACT_NONE,0,1><<<gQ, 256, 0, stream>>>(xn16, WvT, bv, nullptr, vb16, nullptr, MROWS, DIM, DIM);
  mgemm_kernel<ACT_NONE,0,2><<<gQ, 256, 0, stream>>>(xn16, WzT, bz, zb, zb16, nullptr, MROWS, DIM, DIM);

  mgemm_kernel<ACT_RELU,0,1><<<dim3(2,32), 256, 0, stream>>>(zb16, WdT, bd, nullptr, dbuf16, nullptr, MROWS, RDIM, DIM);
  mgemm_kernel<ACT_SIGCLIP,0,0><<<gQ, 256, 0, stream>>>(dbuf16, WuT, bu, gmb, nullptr, nullptr, MROWS, DIM, RDIM);

  scan_sums_kernel<<<dim3(NCH, 8), 256, 0, stream>>>(gmb, ssum);
  scan_apply_kernel<<<dim3(NCH, 8), 256, 0, stream>>>(gmb, ssum, kb16);

  hipMemsetAsync(flg, 0, 786432*sizeof(int), stream);
  rec3_kernel<<<RNG*RG, 512, REC_LDS, stream>>>(zb, gmb, Wg, bg, hseq, hbuf, flg);

  transw_kernel<<<dim3(128,32), 256, 0, stream>>>(Wf1, Wf1T, 1024, 4096);
  transw_kernel<<<dim3(32,128), 256, 0, stream>>>(Wf2, Wf2T, 4096, 1024);

  mattn_kernel<<<dim3(32, BDIM*NHEAD), 256, 0, stream>>>(qb16, kb16, vb16, ctxb);

  add_kernel<<<(int)(NT/1024), 256, 0, stream>>>(ctxb, hseq, add16);
  mgemm_kernel<ACT_NONE,1,0><<<gQ, 256, 0, stream>>>(add16, WoT, bo, yb, nullptr, x, MROWS, DIM, DIM);

  rmsnorm_kernel<<<MROWS, 256, 0, stream>>>(yb, wn2, yn16);
  mgemm_kernel<ACT_GELU,0,1><<<dim3(32,32), 256, 0, stream>>>(yn16, Wf1T, bf1, nullptr, mid16, nullptr, MROWS, FDIM, DIM);
  mgemm_kernel<ACT_NONE,1,0><<<gQ, 256, 0, stream>>>(mid16, Wf2T, bf2, outp, nullptr, yb, MROWS, DIM, FDIM);
}